// Round 2
// baseline (2614.336 us; speedup 1.0000x reference)
//
#include <hip/hip_runtime.h>
#include <hip/hip_bf16.h>
#include <hip/hip_fp16.h>

#define B 256
#define L 128
#define F 256
#define S 512
#define G4 1024  // 4*F gate rows

__device__ __forceinline__ float sigf(float x) { return 1.0f / (1.0f + expf(-x)); }

typedef _Float16 h2raw __attribute__((ext_vector_type(2)));

__device__ __forceinline__ float fdot2(__half2 a, __half2 b, float c) {
#if __has_builtin(__builtin_amdgcn_fdot2)
    return __builtin_amdgcn_fdot2(__builtin_bit_cast(h2raw, a), __builtin_bit_cast(h2raw, b), c, false);
#else
    float2 af = __half22float2(a), bf = __half22float2(b);
    return c + af.x * bf.x + af.y * bf.y;
#endif
}

// Build combined W = W_ih + W_hh, transposed + packed as half2 pairs along k:
// WcT[kp][row] = half2( W[row][2kp], W[row][2kp+1] ),  kp in [0,128), row in [0,1024)
__global__ void prep_kernel(const float* __restrict__ Wih,
                            const float* __restrict__ Whh,
                            const float* __restrict__ bih,
                            const float* __restrict__ bhh,
                            __half2* __restrict__ WcT, float* __restrict__ bias_sum) {
    int row = blockIdx.x * blockDim.x + threadIdx.x;
    if (row >= G4) return;
    bias_sum[row] = bih[row] + bhh[row];
    for (int kp = 0; kp < F / 2; ++kp) {
        float w0 = Wih[row * F + 2 * kp]     + Whh[row * F + 2 * kp];
        float w1 = Wih[row * F + 2 * kp + 1] + Whh[row * F + 2 * kp + 1];
        WcT[kp * G4 + row] = __floats2half2_rn(w0, w1);
    }
}

// init = elu(x[0] @ Wi.T + bi) -> h0, c0 (fp32 in workspace)
__global__ void init_kernel(const float* __restrict__ x,
                            const float* __restrict__ Wi,
                            const float* __restrict__ bi,
                            float* __restrict__ h, float* __restrict__ c) {
    __shared__ float xs[L];
    int b = blockIdx.x, j = threadIdx.x;
    if (j < L) xs[j] = x[b * L + j];
    __syncthreads();
    float acc = bi[j];
    for (int k = 0; k < L; ++k) acc += xs[k] * Wi[j * L + k];
    float v = acc > 0.0f ? acc : expm1f(acc);
    h[b * F + j] = v;
    c[b * F + j] = v;
}

// Step 0: gates = last_feat @ W_ih.T + h0 @ W_hh.T + bias ; writes outs[0] = h1, updates h,c
__global__ void step0_kernel(const float* __restrict__ lf,
                             const float* __restrict__ Wih,
                             const float* __restrict__ Whh,
                             const float* __restrict__ bias_sum,
                             float* __restrict__ h, float* __restrict__ c,
                             float* __restrict__ out) {
    __shared__ float inp[F];
    __shared__ float h0[F];
    int b = blockIdx.x, j = threadIdx.x;
    inp[j] = lf[b * F + j];
    h0[j] = h[b * F + j];
    __syncthreads();
    float a0 = bias_sum[0 * F + j];
    float a1 = bias_sum[1 * F + j];
    float a2 = bias_sum[2 * F + j];
    float a3 = bias_sum[3 * F + j];
    for (int k = 0; k < F; ++k) {
        float ik = inp[k], hk = h0[k];
        a0 += ik * Wih[(0 * F + j) * F + k] + hk * Whh[(0 * F + j) * F + k];
        a1 += ik * Wih[(1 * F + j) * F + k] + hk * Whh[(1 * F + j) * F + k];
        a2 += ik * Wih[(2 * F + j) * F + k] + hk * Whh[(2 * F + j) * F + k];
        a3 += ik * Wih[(3 * F + j) * F + k] + hk * Whh[(3 * F + j) * F + k];
    }
    float c0v = c[b * F + j];
    float c1v = sigf(a1) * c0v + sigf(a0) * tanhf(a2);
    float h1v = sigf(a3) * tanhf(c1v);
    h[b * F + j] = h1v;
    c[b * F + j] = c1v;
    out[(size_t)b * F + j] = h1v;  // t=0 row
}

// Main recurrence: one block per batch element, steps t=1..511.
// 1024 threads: j = tid&255 (hidden unit), q = tid>>8 (k-quarter).
__launch_bounds__(1024, 1)
__global__ void lstm_main(const __half2* __restrict__ WcT,
                          const float* __restrict__ bias_sum,
                          const float* __restrict__ h_in,
                          const float* __restrict__ c_in,
                          float* __restrict__ out) {
    int b = blockIdx.x;
    int tid = threadIdx.x;
    int j = tid & (F - 1);
    int q = tid >> 8;

    __shared__ __half2 hbuf[2][F / 2];       // packed h, double-buffered
    __shared__ float partial[3][4][F];       // partial sums from quarters 1..3

    float b0 = 0.f, b1 = 0.f, b2 = 0.f, b3 = 0.f, cj = 0.f;
    if (q == 0) {
        b0 = bias_sum[0 * F + j];
        b1 = bias_sum[1 * F + j];
        b2 = bias_sum[2 * F + j];
        b3 = bias_sum[3 * F + j];
        cj = c_in[b * F + j];
    }
    if (tid < F / 2) {
        hbuf[0][tid] = __floats2half2_rn(h_in[b * F + 2 * tid], h_in[b * F + 2 * tid + 1]);
    }
    __syncthreads();

    int cur = 0;
    for (int t = 1; t < S; ++t) {
        float a0 = 0.f, a1 = 0.f, a2 = 0.f, a3 = 0.f;
        const int kp0 = q * (F / 8);  // 32 kp per quarter
        #pragma unroll 8
        for (int kk = 0; kk < F / 8; ++kk) {
            int kp = kp0 + kk;
            __half2 hv = hbuf[cur][kp];
            const __half2* wp = WcT + (size_t)kp * G4 + j;
            a0 = fdot2(wp[0 * F], hv, a0);
            a1 = fdot2(wp[1 * F], hv, a1);
            a2 = fdot2(wp[2 * F], hv, a2);
            a3 = fdot2(wp[3 * F], hv, a3);
        }
        if (q > 0) {
            partial[q - 1][0][j] = a0;
            partial[q - 1][1][j] = a1;
            partial[q - 1][2][j] = a2;
            partial[q - 1][3][j] = a3;
        }
        __syncthreads();
        if (q == 0) {
            #pragma unroll
            for (int p = 0; p < 3; ++p) {
                a0 += partial[p][0][j];
                a1 += partial[p][1][j];
                a2 += partial[p][2][j];
                a3 += partial[p][3][j];
            }
            a0 += b0; a1 += b1; a2 += b2; a3 += b3;
            float c2 = sigf(a1) * cj + sigf(a0) * tanhf(a2);
            float h2 = sigf(a3) * tanhf(c2);
            cj = c2;
            out[((size_t)t * B + b) * F + j] = h2;
            ((__half*)hbuf[cur ^ 1])[j] = __float2half(h2);
        }
        __syncthreads();
        cur ^= 1;
    }
}

extern "C" void kernel_launch(void* const* d_in, const int* in_sizes, int n_in,
                              void* d_out, int out_size, void* d_ws, size_t ws_size,
                              hipStream_t stream) {
    const float* x   = (const float*)d_in[0];
    const float* lf  = (const float*)d_in[1];
    const float* Wi  = (const float*)d_in[2];
    const float* bi  = (const float*)d_in[3];
    const float* Wih = (const float*)d_in[4];
    const float* Whh = (const float*)d_in[5];
    const float* bih = (const float*)d_in[6];
    const float* bhh = (const float*)d_in[7];
    // d_in[8], d_in[9] (Wo, bo): computed-and-discarded in the reference; unused.
    float* out = (float*)d_out;

    float* ws     = (float*)d_ws;
    float* h      = ws;              // 65536 floats
    float* c      = ws + 65536;      // 65536 floats
    float* bias   = ws + 131072;     // 1024 floats
    __half2* WcT  = (__half2*)(ws + 132096);  // 131072 half2 = 512 KB

    prep_kernel<<<4, 256, 0, stream>>>(Wih, Whh, bih, bhh, WcT, bias);
    init_kernel<<<B, F, 0, stream>>>(x, Wi, bi, h, c);
    step0_kernel<<<B, F, 0, stream>>>(lf, Wih, Whh, bias, h, c, out);
    lstm_main<<<B, 1024, 0, stream>>>(WcT, bias, h, c, out);
}

// Round 3
// 1796.659 us; speedup vs baseline: 1.4551x; 1.4551x over previous
//
#include <hip/hip_runtime.h>
#include <hip/hip_bf16.h>
#include <hip/hip_fp16.h>

#define B 256
#define L 128
#define F 256
#define S 512
#define G4 1024  // 4*F gate rows

typedef _Float16 h2raw __attribute__((ext_vector_type(2)));

__device__ __forceinline__ float fdot2u(unsigned a, unsigned b, float c) {
#if __has_builtin(__builtin_amdgcn_fdot2)
    return __builtin_amdgcn_fdot2(__builtin_bit_cast(h2raw, a), __builtin_bit_cast(h2raw, b), c, false);
#else
    __half2 ah = __builtin_bit_cast(__half2, a), bh = __builtin_bit_cast(__half2, b);
    float2 af = __half22float2(ah), bf = __half22float2(bh);
    return c + af.x * bf.x + af.y * bf.y;
#endif
}

// fast device transcendentals: v_exp_f32 / v_rcp_f32 based
__device__ __forceinline__ float fast_rcp(float x) { return __builtin_amdgcn_rcpf(x); }
__device__ __forceinline__ float sigf(float x) {
    float e = __expf(-x);             // v_mul + v_exp
    return fast_rcp(1.0f + e);        // safe: e=inf -> rcp(inf)=0; e=0 -> 1
}
__device__ __forceinline__ float tanhf_fast(float x) {
    x = fminf(fmaxf(x, -15.0f), 15.0f);  // avoid inf/inf NaN; tanh saturated anyway
    float e = __expf(-2.0f * x);
    return (1.0f - e) * fast_rcp(1.0f + e);
}

template <int CTRL>
__device__ __forceinline__ float dpp_add(float x) {
    int v = __builtin_amdgcn_update_dpp(0, __builtin_bit_cast(int, x), CTRL, 0xF, 0xF, true);
    return x + __builtin_bit_cast(float, v);
}

// Prep: pack combined W = W_ih + W_hh into the main kernel's register-load layout.
// Wpk[m][tid] (16B each, m<32, tid<1024): for thread tid (j=tid>>2, q=tid&3), load m
// (g=m>>3, kk8=m&7) holds 4 half2 = k-pairs kp0..kp0+3 of row r=g*256+j, kp0=q*32+kk8*4.
__global__ void prep_kernel(const float* __restrict__ Wih,
                            const float* __restrict__ Whh,
                            const float* __restrict__ bih,
                            const float* __restrict__ bhh,
                            uint4* __restrict__ Wpk, float* __restrict__ bias_sum) {
    int e = blockIdx.x * blockDim.x + threadIdx.x;  // 32768 elements
    if (e < G4) bias_sum[e] = bih[e] + bhh[e];
    int m = e >> 10, tid = e & 1023;
    int j = tid >> 2, q = tid & 3;
    int g = m >> 3, kk8 = m & 7;
    int r = g * F + j;
    int kp0 = q * 32 + kk8 * 4;
    unsigned pk[4];
    #pragma unroll
    for (int i = 0; i < 4; ++i) {
        int k = 2 * (kp0 + i);
        float w0 = Wih[r * F + k]     + Whh[r * F + k];
        float w1 = Wih[r * F + k + 1] + Whh[r * F + k + 1];
        pk[i] = __builtin_bit_cast(unsigned, __floats2half2_rn(w0, w1));
    }
    Wpk[(size_t)m * 1024 + tid] = make_uint4(pk[0], pk[1], pk[2], pk[3]);
}

// init = elu(x[0] @ Wi.T + bi) -> h0, c0 (fp32 in workspace)
__global__ void init_kernel(const float* __restrict__ x,
                            const float* __restrict__ Wi,
                            const float* __restrict__ bi,
                            float* __restrict__ h, float* __restrict__ c) {
    __shared__ float xs[L];
    int b = blockIdx.x, j = threadIdx.x;
    if (j < L) xs[j] = x[b * L + j];
    __syncthreads();
    float acc = bi[j];
    for (int k = 0; k < L; ++k) acc += xs[k] * Wi[j * L + k];
    float v = acc > 0.0f ? acc : expm1f(acc);
    h[b * F + j] = v;
    c[b * F + j] = v;
}

// Step 0: gates = last_feat @ W_ih.T + h0 @ W_hh.T + bias ; writes outs[0], updates h,c
__global__ void step0_kernel(const float* __restrict__ lf,
                             const float* __restrict__ Wih,
                             const float* __restrict__ Whh,
                             const float* __restrict__ bias_sum,
                             float* __restrict__ h, float* __restrict__ c,
                             float* __restrict__ out) {
    __shared__ float inp[F];
    __shared__ float h0[F];
    int b = blockIdx.x, j = threadIdx.x;
    inp[j] = lf[b * F + j];
    h0[j] = h[b * F + j];
    __syncthreads();
    float a0 = bias_sum[0 * F + j];
    float a1 = bias_sum[1 * F + j];
    float a2 = bias_sum[2 * F + j];
    float a3 = bias_sum[3 * F + j];
    for (int k = 0; k < F; ++k) {
        float ik = inp[k], hk = h0[k];
        a0 += ik * Wih[(0 * F + j) * F + k] + hk * Whh[(0 * F + j) * F + k];
        a1 += ik * Wih[(1 * F + j) * F + k] + hk * Whh[(1 * F + j) * F + k];
        a2 += ik * Wih[(2 * F + j) * F + k] + hk * Whh[(2 * F + j) * F + k];
        a3 += ik * Wih[(3 * F + j) * F + k] + hk * Whh[(3 * F + j) * F + k];
    }
    float c0v = c[b * F + j];
    float c1v = sigf(a1) * c0v + sigf(a0) * tanhf_fast(a2);
    float h1v = sigf(a3) * tanhf_fast(c1v);
    h[b * F + j] = h1v;
    c[b * F + j] = c1v;
    out[(size_t)b * F + j] = h1v;  // t=0 row
}

// Main recurrence, weight-stationary in VGPRs. One block per batch element.
// 1024 threads: j = tid>>2 (hidden unit), q = tid&3 (k-quarter, reduced via DPP quad_perm).
__launch_bounds__(1024, 1)
__global__ void lstm_main(const uint4* __restrict__ Wpk,
                          const float* __restrict__ bias_sum,
                          const float* __restrict__ h_in,
                          const float* __restrict__ c_in,
                          float* __restrict__ out) {
    int b = blockIdx.x;
    int tid = threadIdx.x;
    int j = tid >> 2;
    int q = tid & 3;

    __shared__ __half hbuf[2][F];  // double-buffered hidden state, f16

    // One-time: weights into registers (128 VGPRs/thread), coalesced.
    uint4 w[32];
    #pragma unroll
    for (int m = 0; m < 32; ++m) w[m] = Wpk[(size_t)m * 1024 + tid];

    float bias[4];
    #pragma unroll
    for (int g = 0; g < 4; ++g) bias[g] = bias_sum[g * F + j];
    float cj = c_in[b * F + j];

    if (tid < F) hbuf[0][tid] = __float2half(h_in[b * F + tid]);
    __syncthreads();

    int cur = 0;
    for (int t = 1; t < S; ++t) {
        // my 64-half k-slice of h: 8 x 16B
        const uint4* hp = (const uint4*)(&hbuf[cur][q * 64]);
        uint4 hr[8];
        #pragma unroll
        for (int i = 0; i < 8; ++i) hr[i] = hp[i];

        float a[4];
        #pragma unroll
        for (int g = 0; g < 4; ++g) {
            float acc = 0.0f;
            #pragma unroll
            for (int i = 0; i < 8; ++i) {
                uint4 wv = w[g * 8 + i];
                acc = fdot2u(wv.x, hr[i].x, acc);
                acc = fdot2u(wv.y, hr[i].y, acc);
                acc = fdot2u(wv.z, hr[i].z, acc);
                acc = fdot2u(wv.w, hr[i].w, acc);
            }
            a[g] = acc;
        }
        // quad butterfly: sum the 4 k-quarters (lanes j*4+0..3); all lanes get full sum
        #pragma unroll
        for (int g = 0; g < 4; ++g) {
            a[g] = dpp_add<0xB1>(a[g]);  // quad_perm [1,0,3,2]: xor 1
            a[g] = dpp_add<0x4E>(a[g]);  // quad_perm [2,3,0,1]: xor 2
            a[g] += bias[g];
        }
        float c2 = sigf(a[1]) * cj + sigf(a[0]) * tanhf_fast(a[2]);
        float h2 = sigf(a[3]) * tanhf_fast(c2);
        cj = c2;
        if (q == 0) {
            hbuf[cur ^ 1][j] = __float2half(h2);
            out[((size_t)t * B + b) * F + j] = h2;
        }
        __syncthreads();
        cur ^= 1;
    }
}

extern "C" void kernel_launch(void* const* d_in, const int* in_sizes, int n_in,
                              void* d_out, int out_size, void* d_ws, size_t ws_size,
                              hipStream_t stream) {
    const float* x   = (const float*)d_in[0];
    const float* lf  = (const float*)d_in[1];
    const float* Wi  = (const float*)d_in[2];
    const float* bi  = (const float*)d_in[3];
    const float* Wih = (const float*)d_in[4];
    const float* Whh = (const float*)d_in[5];
    const float* bih = (const float*)d_in[6];
    const float* bhh = (const float*)d_in[7];
    // d_in[8], d_in[9] (Wo, bo): computed-and-discarded in the reference; unused.
    float* out = (float*)d_out;

    float* ws    = (float*)d_ws;
    float* h     = ws;               // 65536 floats
    float* c     = ws + 65536;       // 65536 floats
    float* bias  = ws + 131072;      // 1024 floats
    uint4* Wpk   = (uint4*)(ws + 132096);  // 32768 x 16B = 512 KB

    prep_kernel<<<128, 256, 0, stream>>>(Wih, Whh, bih, bhh, Wpk, bias);
    init_kernel<<<B, F, 0, stream>>>(x, Wi, bi, h, c);
    step0_kernel<<<B, F, 0, stream>>>(lf, Wih, Whh, bias, h, c, out);
    lstm_main<<<B, 1024, 0, stream>>>(Wpk, bias, h, c, out);
}